// Round 10
// baseline (317.484 us; speedup 1.0000x reference)
//
#include <hip/hip_runtime.h>
#include <hip/hip_bf16.h>

// Problem constants (fixed by reference)
#define NN 512
#define EE 2048
#define LL 16
#define FF 16
#define MM 8
#define HH 128
#define CAP_ROWS 40960             // packed rows across all egos (~34k expected, u16 ids)
#define MAXD 32                    // per-node / per-row neighbor capacity (avg deg ~8)
#define TAU_SCALE 14.426950408889634f   // log2(e)/TAU, TAU=0.1

typedef __attribute__((ext_vector_type(8))) short bf16x8;   // 8 bf16 = 4 VGPR
typedef __attribute__((ext_vector_type(8))) unsigned short u16x8;
typedef __attribute__((ext_vector_type(4))) float f32x4;

// ---- workspace layout (bytes) ----
constexpr size_t OFF_ADJ   = 0;                              // u64[512*8] adjacency bitsets (memset)
constexpr size_t SZ_ADJ    = (size_t)NN * 8 * 8;
constexpr size_t OFF_DEG   = OFF_ADJ + SZ_ADJ;               // int[512] node degree (memset)
constexpr size_t SZ_DEG    = (size_t)NN * 4;
constexpr size_t OFF_CNT   = OFF_DEG + SZ_DEG;               // int[512] ego node counts
constexpr size_t SZ_CNT    = (size_t)NN * 4;
constexpr size_t OFF_ROFF  = OFF_CNT + SZ_CNT;               // int[513] packed row offsets
constexpr size_t SZ_ROFF   = (size_t)(NN + 1) * 4 + 12;
constexpr size_t OFF_BUCKN = OFF_ROFF + SZ_ROFF;             // int[512] node -> WL bucket
constexpr size_t SZ_BUCKN  = (size_t)NN * 4;
constexpr size_t OFF_BUCKF = OFF_BUCKN + SZ_BUCKN;           // int[128]
constexpr size_t SZ_BUCKF  = (size_t)FF * MM * 4;
constexpr size_t OFF_NLST  = ((OFF_BUCKF + SZ_BUCKF + 63) / 64) * 64;  // u16[512*32] node nbr lists
constexpr size_t SZ_NLST   = (size_t)NN * MAXD * 2;
constexpr size_t OFF_CEGO  = OFF_NLST + SZ_NLST;             // u16[CAP] row -> ego
constexpr size_t SZ_CEGO   = (size_t)CAP_ROWS * 2;
constexpr size_t OFF_NCNT  = OFF_CEGO + SZ_CEGO;             // u16[CAP] row nbr count
constexpr size_t SZ_NCNT   = (size_t)CAP_ROWS * 2;
constexpr size_t OFF_RBK   = OFF_NCNT + SZ_NCNT;             // u16[CAP] row -> own bucket
constexpr size_t SZ_RBK    = (size_t)CAP_ROWS * 2;
constexpr size_t OFF_NBR   = OFF_RBK + SZ_RBK;               // u16[CAP*32] row nbr -> packed row id
constexpr size_t SZ_NBR    = (size_t)CAP_ROWS * MAXD * 2;
constexpr size_t OFF_NBK   = OFF_NBR + SZ_NBR;               // u16[CAP*32] row nbr -> bucket
constexpr size_t SZ_NBK    = (size_t)CAP_ROWS * MAXD * 2;
constexpr size_t OFF_EGOF  = ((OFF_NBK + SZ_NBK + 63) / 64) * 64;      // f32[512*512] ego feats
constexpr size_t SZ_EGOF   = (size_t)NN * 512 * 4;
constexpr size_t OFF_FILTF = OFF_EGOF + SZ_EGOF;             // f32[16*512]
constexpr size_t SZ_FILTF  = (size_t)FF * 512 * 4;
constexpr size_t OFF_FNORM = OFF_FILTF + SZ_FILTF;           // f32[16]
constexpr size_t SZ_FNORM  = 64;
constexpr size_t OFF_CA    = ((OFF_FNORM + SZ_FNORM + 255) / 256) * 256; // c buf A [CAP*128] f32
constexpr size_t SZ_CBUF   = (size_t)CAP_ROWS * HH * 4;      // 20 MB
constexpr size_t OFF_CB    = OFF_CA + SZ_CBUF;               // c buf B
constexpr size_t OFF_RT    = OFF_CB + SZ_CBUF;               // bf16 RtH (64K) + RtL (64K)
// total ~ 49.5 MB

// ---- bf16 split helpers (RNE) ----
__device__ __forceinline__ unsigned f2bfbits(float x) {
    unsigned u = __float_as_uint(x);
    return (u + 0x7fffu + ((u >> 16) & 1u)) >> 16;
}
__device__ __forceinline__ float bf2f(unsigned hb) { return __uint_as_float(hb << 16); }

// XCD-aware bijective block swizzle (requires nwg % 8 == 0): XCD k gets a
// CONTIGUOUS chunk of the grid -> intra-ego gathers stay in k's private L2.
__device__ __forceinline__ int xcd_swz(int bid, int nwg) {
    int cpx = nwg >> 3;
    return (bid & 7) * cpx + (bid >> 3);
}

// ---------------------------------------------------------------------------
// K1: node degree + nbr lists + adjacency bitsets + bucket lookups
//     + (merged) R -> transposed bf16 hi/lo Rt[col][k].
// ---------------------------------------------------------------------------
__global__ __launch_bounds__(256) void k_build(const int* __restrict__ ei,
                                               const float* __restrict__ x,
                                               const float* __restrict__ X,
                                               const float* __restrict__ E0,
                                               const float* __restrict__ Rg,
                                               int* __restrict__ degN,
                                               unsigned short* __restrict__ nbrLstN,
                                               unsigned long long* __restrict__ adj,
                                               int* __restrict__ buckN,
                                               int* __restrict__ buckF,
                                               short* __restrict__ RtH,
                                               short* __restrict__ RtL) {
    int idx = blockIdx.x * blockDim.x + threadIdx.x;
    if (idx < EE) {
        int a = ei[idx], b = ei[EE + idx];
        int p = atomicAdd(&degN[a], 1);
        if (p < MAXD) nbrLstN[(size_t)a * MAXD + p] = (unsigned short)b;
        int q = atomicAdd(&degN[b], 1);
        if (q < MAXD) nbrLstN[(size_t)b * MAXD + q] = (unsigned short)a;
        atomicOr(&adj[(size_t)a * 8 + (b >> 6)], 1ull << (b & 63));
        atomicOr(&adj[(size_t)b * 8 + (a >> 6)], 1ull << (a & 63));
    } else if (idx < EE + NN) {
        int i = idx - EE;
        int lab = 0;
        for (int l = 0; l < LL; ++l) if (x[i * LL + l] > 0.5f) lab = l;
        int b = 0;
        for (int h = 0; h < HH; ++h) if (E0[lab * HH + h] > 0.5f) b = h;
        buckN[i] = b;
    } else if (idx < EE + NN + FF * MM) {
        int fm = idx - EE - NN;
        int lab = 0;
        for (int l = 0; l < LL; ++l) if (X[fm * LL + l] > 0.5f) lab = l;
        int b = 0;
        for (int h = 0; h < HH; ++h) if (E0[lab * HH + h] > 0.5f) b = h;
        buckF[fm] = b;
    } else if (idx < EE + NN + FF * MM + 4096) {
        int pidx = idx - (EE + NN + FF * MM);
        int col = pidx >> 5;
        int kc = (pidx & 31) * 8;
        bf16x8 hv, lv;
#pragma unroll
        for (int j = 0; j < 8; ++j) {
            float xv = Rg[(size_t)(kc + j) * HH + col];
            unsigned hb = f2bfbits(xv);
            hv[j] = (short)hb;
            lv[j] = (short)f2bfbits(xv - bf2f(hb));
        }
        *(bf16x8*)&RtH[(size_t)col * 256 + kc] = hv;
        *(bf16x8*)&RtL[(size_t)col * 256 + kc] = lv;
    }
}

// ---------------------------------------------------------------------------
// K2: 2-hop reach bitsets + counts (256 threads, 4 waves x 2 bit-words).
// ---------------------------------------------------------------------------
__global__ __launch_bounds__(256, 2) void k_reach(const unsigned long long* __restrict__ adj,
                                                  unsigned long long* __restrict__ bitsR,
                                                  int* __restrict__ count) {
    __shared__ unsigned long long r1[8];
    __shared__ unsigned long long r2[8];
    int i = blockIdx.x, tid = threadIdx.x;
    int t = tid & 63, w = tid >> 6;
    if (tid < 8) {
        unsigned long long v = adj[(size_t)i * 8 + tid];
        if (tid == (i >> 6)) v |= 1ull << (i & 63);
        r1[tid] = v;
        r2[tid] = v;
    }
    __syncthreads();
    unsigned long long p[8] = {0, 0, 0, 0, 0, 0, 0, 0};
#pragma unroll
    for (int rr = 0; rr < 2; ++rr) {
        int rep = 2 * w + rr;
        if ((r1[rep] >> t) & 1ull) {
            int j = t + rep * 64;
#pragma unroll
            for (int w2 = 0; w2 < 8; ++w2) p[w2] |= adj[(size_t)j * 8 + w2];
        }
    }
#pragma unroll
    for (int w2 = 0; w2 < 8; ++w2)
        if (p[w2]) atomicOr(&r2[w2], p[w2]);
    __syncthreads();
    if (tid < 8) bitsR[(size_t)i * 8 + tid] = r2[tid];
    if (tid == 0) {
        int acc = 0;
        for (int w2 = 0; w2 < 8; ++w2) acc += __popcll(r2[w2]);
        count[i] = acc;
    }
}

// ---------------------------------------------------------------------------
// K3: pack egos into flat row space (inline prefix scan, writes rowOff).
// ---------------------------------------------------------------------------
__global__ __launch_bounds__(64) void k_pack(const unsigned long long* __restrict__ bitsR,
                                             const int* __restrict__ count,
                                             int* __restrict__ rowOff,
                                             const int* __restrict__ degN,
                                             const unsigned short* __restrict__ nbrLstN,
                                             const int* __restrict__ buckN,
                                             unsigned short* __restrict__ nbrRow,
                                             unsigned short* __restrict__ nbrBuck,
                                             unsigned short* __restrict__ nbrCnt,
                                             unsigned short* __restrict__ rowBuck,
                                             unsigned short* __restrict__ cegoG,
                                             float* __restrict__ egoF) {
    __shared__ unsigned long long bits[8];
    __shared__ int wpre[8];
    __shared__ unsigned short cmap_s[NN];
    __shared__ unsigned short nodes_s[NN];
    __shared__ int buckS[NN];
    __shared__ float f0[HH];
    int i = blockIdx.x, t = threadIdx.x;
    // ---- inline exclusive prefix: base = sum(count[0..i-1]) ----
    int pre = 0;
#pragma unroll
    for (int j = 0; j < 8; ++j) {
        int idx = t * 8 + j;
        int cj = count[idx];
        if (idx < i) pre += cj;
    }
    for (int off = 32; off > 0; off >>= 1) pre += __shfl_xor(pre, off);
    int base = pre;
    if (t == 0) {
        rowOff[i] = base;
        if (i == NN - 1) rowOff[NN] = base + count[i];
    }
    if (t < 8) bits[t] = bitsR[(size_t)i * 8 + t];
    { f0[t] = 0.0f; f0[t + 64] = 0.0f; }
    for (int j = t; j < NN; j += 64) buckS[j] = buckN[j];
    __syncthreads();
    if (t == 0) {
        int acc = 0;
        for (int w = 0; w < 8; ++w) { wpre[w] = acc; acc += __popcll(bits[w]); }
    }
    __syncthreads();
    int n = count[i];
    if (base >= CAP_ROWS) n = 0;
    else if (base + n > CAP_ROWS) n = CAP_ROWS - base;
    for (int rep = 0; rep < 8; ++rep) {
        int j = t + rep * 64;
        unsigned long long word = bits[rep];
        unsigned short v = 0xFFFFu;
        if ((word >> t) & 1ull) {
            int idx = wpre[rep] + __popcll(word & ((1ull << t) - 1ull));
            if (idx < n) { v = (unsigned short)idx; nodes_s[idx] = (unsigned short)j; }
        }
        cmap_s[j] = v;
    }
    // zero iter 2..3 feats region (iter 0,1 fully overwritten)
    for (int q = 256 + t; q < 512; q += 64) egoF[(size_t)i * 512 + q] = 0.0f;
    __syncthreads();
    for (int m = t; m < n; m += 64) {
        int j = nodes_s[m];
        int b = buckS[j];
        atomicAdd(&f0[b], 1.0f);
        size_t row = (size_t)(base + m);
        rowBuck[row] = (unsigned short)b;
        int dn = degN[j]; if (dn > MAXD) dn = MAXD;
        int cnt = 0;
        for (int eb = 0; eb < dn; eb += 8) {
            u16x8 nv = *(const u16x8*)&nbrLstN[(size_t)j * MAXD + eb];
#pragma unroll
            for (int j8 = 0; j8 < 8; ++j8) {
                if (eb + j8 < dn) {
                    unsigned short nbNode = nv[j8];
                    unsigned short nr = cmap_s[nbNode];
                    if (nr != 0xFFFFu && cnt < MAXD) {
                        nbrRow[row * MAXD + cnt] = (unsigned short)(base + nr);
                        nbrBuck[row * MAXD + cnt] = (unsigned short)buckS[nbNode];
                        cnt++;
                    }
                }
            }
        }
        nbrCnt[row] = (unsigned short)cnt;
        cegoG[row] = (unsigned short)i;
    }
    __syncthreads();
    if (t < 64) {
        egoF[(size_t)i * 512 + t] = f0[t];
        egoF[(size_t)i * 512 + t + 64] = f0[t + 64];
    }
}

// ---------------------------------------------------------------------------
// K4: iteration 1, sparse form (Rbot staged in LDS — r9, neutral-or-better).
// ---------------------------------------------------------------------------
__global__ __launch_bounds__(256, 2) void k_iter1(const int* __restrict__ count,
                                                  const int* __restrict__ rowOff,
                                                  const unsigned short* __restrict__ rowBuck,
                                                  const unsigned short* __restrict__ nbrBuck,
                                                  const unsigned short* __restrict__ nbrCnt,
                                                  const float* __restrict__ Rg,
                                                  float* __restrict__ cOut,
                                                  float* __restrict__ egoF) {
    __shared__ float RbS[HH * HH];      // 64 KB: Rbot rows, linear
    __shared__ float fs[HH];
    int i = xcd_swz(blockIdx.x, NN);
    int tid = threadIdx.x;
    int base = rowOff[i];
    int n = count[i];
    if (base >= CAP_ROWS) n = 0;
    else if (base + n > CAP_ROWS) n = CAP_ROWS - base;
    if (tid < HH) fs[tid] = 0.0f;
    // ---- stage Rbot -> LDS (coalesced float4 stream) ----
    {
        const float4* src = (const float4*)(Rg + (size_t)HH * HH);
        float4* dst = (float4*)RbS;
        for (int idx = tid; idx < (HH * HH) / 4; idx += 256) dst[idx] = src[idx];
    }
    __syncthreads();
    int col = (tid & 7) * 16;
    float facc[16];
#pragma unroll
    for (int q = 0; q < 16; ++q) facc[q] = 0.0f;
    for (int m = tid >> 3; m < n; m += 32) {
        int gr = base + m;
        float z[16];
        const float* rt = Rg + (size_t)rowBuck[gr] * HH + col;
#pragma unroll
        for (int q = 0; q < 4; ++q) *(float4*)&z[q * 4] = *(const float4*)&rt[q * 4];
        int cnt = nbrCnt[gr];
        const unsigned short* nk = &nbrBuck[(size_t)gr * MAXD];
        for (int eb = 0; eb < cnt; eb += 8) {
            u16x8 nv = *(const u16x8*)&nk[eb];
#pragma unroll
            for (int j = 0; j < 8; ++j) {
                if (eb + j < cnt) {
                    const float* rb = RbS + (size_t)nv[j] * HH + col;
#pragma unroll
                    for (int q = 0; q < 4; ++q) {
                        float4 rv = *(const float4*)&rb[q * 4];
                        z[q * 4 + 0] += rv.x; z[q * 4 + 1] += rv.y;
                        z[q * 4 + 2] += rv.z; z[q * 4 + 3] += rv.w;
                    }
                }
            }
        }
        float mx = z[0];
#pragma unroll
        for (int q = 1; q < 16; ++q) mx = fmaxf(mx, z[q]);
        for (int off = 4; off > 0; off >>= 1) mx = fmaxf(mx, __shfl_xor(mx, off));
        float s = 0.0f;
#pragma unroll
        for (int q = 0; q < 16; ++q) { z[q] = exp2f((z[q] - mx) * TAU_SCALE); s += z[q]; }
        for (int off = 4; off > 0; off >>= 1) s += __shfl_xor(s, off);
        float inv = 1.0f / s;
        float* crow = cOut + (size_t)gr * HH + col;
#pragma unroll
        for (int q = 0; q < 16; ++q) { z[q] *= inv; facc[q] += z[q]; }
#pragma unroll
        for (int q = 0; q < 4; ++q) *(float4*)&crow[q * 4] = *(const float4*)&z[q * 4];
    }
#pragma unroll
    for (int q = 0; q < 16; ++q) atomicAdd(&fs[col + q], facc[q]);
    __syncthreads();
    if (tid < HH) egoF[(size_t)i * 512 + HH + tid] = fs[tid];
}

// ---------------------------------------------------------------------------
// K5: fused soft-WL iteration (it=2,3) — r7 per-wave body VERBATIM, v10:
// FOUR independent waves per 256-thread block (wave wid owns tile swz*4+wid).
// Blocks arrive as 4-wave bundles -> 4x resident waves per CU at equal work
// (tests the wave-residency-pacing hypothesis; zero arithmetic change).
// Index chunks preloaded up-front (nbrRow rows are fully-allocated MAXD u16).
// ---------------------------------------------------------------------------
__global__ __launch_bounds__(256, 2) void k_iter(const float* __restrict__ cur,
                                                 float* __restrict__ nxt,
                                                 const short* __restrict__ RtH,
                                                 const short* __restrict__ RtL,
                                                 const int* __restrict__ rowOff,
                                                 const unsigned short* __restrict__ nbrRow,
                                                 const unsigned short* __restrict__ nbrCnt,
                                                 const unsigned short* __restrict__ cegoG,
                                                 float* __restrict__ egoF,
                                                 int it) {
    int Rtot = rowOff[NN];
    if (Rtot > CAP_ROWS) Rtot = CAP_ROWS;
    int tid = threadIdx.x;
    int wid = tid >> 6, lane = tid & 63;
    int r0 = (xcd_swz(blockIdx.x, gridDim.x) * 4 + wid) * 16;
    if (r0 >= Rtot) return;                  // per-wave early-out (no barriers used)
    int c16 = lane & 15, g = lane >> 4;
    int kb = g * 8;                          // this lane's 8-k slice within each 32-k tile
    int grA = r0 + c16;                      // A-row this lane feeds (clamped for loads)
    if (grA >= Rtot) grA = Rtot - 1;

    // ---- own-c fragment loads first (independent, in flight early) ----
    const float* crOwn = &cur[(size_t)grA * HH + kb];
    float4 oc[8];
#pragma unroll
    for (int t = 0; t < 4; ++t) {
        oc[2 * t]     = *(const float4*)&crOwn[t * 32];
        oc[2 * t + 1] = *(const float4*)&crOwn[t * 32 + 4];
    }

    // ---- gather u slices: ALL index chunks preloaded, add order == r1 ----
    float ua[4][8];
#pragma unroll
    for (int s = 0; s < 4; ++s)
#pragma unroll
        for (int j = 0; j < 8; ++j) ua[s][j] = 0.0f;
    {
        int cnt = nbrCnt[grA];
        const unsigned short* nb = &nbrRow[(size_t)grA * MAXD];
        u16x8 nv0 = *(const u16x8*)&nb[0];
        u16x8 nv1 = *(const u16x8*)&nb[8];
        u16x8 nv2 = *(const u16x8*)&nb[16];
        u16x8 nv3 = *(const u16x8*)&nb[24];
#pragma unroll
        for (int cb = 0; cb < 4; ++cb) {
            u16x8 nv = (cb == 0) ? nv0 : (cb == 1) ? nv1 : (cb == 2) ? nv2 : nv3;
            int eb = cb * 8;
            if (eb < cnt) {
#pragma unroll
                for (int j = 0; j < 8; ++j) {
                    if (eb + j < cnt) {
                        const float* cr = &cur[(size_t)nv[j] * HH + kb];
#pragma unroll
                        for (int s = 0; s < 4; ++s) {
                            float4 v0 = *(const float4*)&cr[s * 32];
                            float4 v1 = *(const float4*)&cr[s * 32 + 4];
                            ua[s][0] += v0.x; ua[s][1] += v0.y; ua[s][2] += v0.z; ua[s][3] += v0.w;
                            ua[s][4] += v1.x; ua[s][5] += v1.y; ua[s][6] += v1.z; ua[s][7] += v1.w;
                        }
                    }
                }
            }
        }
    }

    f32x4 acc[8];
#pragma unroll
    for (int n = 0; n < 8; ++n) acc[n] = (f32x4)(0.0f);
    const short* bbH = RtH + (size_t)c16 * 256 + kb;
    const short* bbL = RtL + (size_t)c16 * 256 + kb;

    // ---- u ktiles (t = s+4), converting+releasing one 8-reg slice at a time ----
#pragma unroll
    for (int s = 0; s < 4; ++s) {
        bf16x8 ahi, alo;
#pragma unroll
        for (int j = 0; j < 8; ++j) {
            float xv = ua[s][j];
            unsigned hb = f2bfbits(xv);
            ahi[j] = (short)hb;
            alo[j] = (short)f2bfbits(xv - bf2f(hb));
        }
        const int t = s + 4;
#pragma unroll
        for (int n = 0; n < 8; ++n) {
            bf16x8 bh = *(const bf16x8*)&bbH[n * 4096 + t * 32];
            bf16x8 bl = *(const bf16x8*)&bbL[n * 4096 + t * 32];
            acc[n] = __builtin_amdgcn_mfma_f32_16x16x32_bf16(ahi, bh, acc[n], 0, 0, 0);
            acc[n] = __builtin_amdgcn_mfma_f32_16x16x32_bf16(ahi, bl, acc[n], 0, 0, 0);
            acc[n] = __builtin_amdgcn_mfma_f32_16x16x32_bf16(alo, bh, acc[n], 0, 0, 0);
        }
    }
    // ---- c ktiles (t = 0..3), from the hoisted oc regs ----
    {
#pragma unroll
        for (int t = 0; t < 4; ++t) {
            float4 v0 = oc[2 * t];
            float4 v1 = oc[2 * t + 1];
            float cv[8] = {v0.x, v0.y, v0.z, v0.w, v1.x, v1.y, v1.z, v1.w};
            bf16x8 ahi, alo;
#pragma unroll
            for (int j = 0; j < 8; ++j) {
                unsigned hb = f2bfbits(cv[j]);
                ahi[j] = (short)hb;
                alo[j] = (short)f2bfbits(cv[j] - bf2f(hb));
            }
#pragma unroll
            for (int n = 0; n < 8; ++n) {
                bf16x8 bh = *(const bf16x8*)&bbH[n * 4096 + t * 32];
                bf16x8 bl = *(const bf16x8*)&bbL[n * 4096 + t * 32];
                acc[n] = __builtin_amdgcn_mfma_f32_16x16x32_bf16(ahi, bh, acc[n], 0, 0, 0);
                acc[n] = __builtin_amdgcn_mfma_f32_16x16x32_bf16(ahi, bl, acc[n], 0, 0, 0);
                acc[n] = __builtin_amdgcn_mfma_f32_16x16x32_bf16(alo, bh, acc[n], 0, 0, 0);
            }
        }
    }

    // ---- softmax per output row (row = 4g+i lives in 16 lanes x 8 regs) ----
    float inv[4];
#pragma unroll
    for (int i = 0; i < 4; ++i) {
        float m = acc[0][i];
#pragma unroll
        for (int n = 1; n < 8; ++n) m = fmaxf(m, acc[n][i]);
        for (int off = 8; off > 0; off >>= 1) m = fmaxf(m, __shfl_xor(m, off));
        float s = 0.0f;
#pragma unroll
        for (int n = 0; n < 8; ++n) {
            float e = exp2f((acc[n][i] - m) * TAU_SCALE);
            acc[n][i] = e; s += e;
        }
        for (int off = 8; off > 0; off >>= 1) s += __shfl_xor(s, off);
        inv[i] = 1.0f / s;
    }

    // ---- store c_next + per-ego feature accumulation ----
    float fa[8];
#pragma unroll
    for (int n = 0; n < 8; ++n) fa[n] = 0.0f;
    int cege = -1;
#pragma unroll
    for (int i = 0; i < 4; ++i) {
        int gr = r0 + g * 4 + i;
        if (gr < Rtot) {
#pragma unroll
            for (int n = 0; n < 8; ++n) {
                float c = acc[n][i] * inv[i];
                nxt[(size_t)gr * HH + n * 16 + c16] = c;
                acc[n][i] = c;
            }
            int ego = cegoG[gr];
            if (ego != cege) {
                if (cege >= 0) {
#pragma unroll
                    for (int n = 0; n < 8; ++n) {
                        atomicAdd(&egoF[(size_t)cege * 512 + it * HH + n * 16 + c16], fa[n]);
                        fa[n] = 0.0f;
                    }
                }
                cege = ego;
            }
#pragma unroll
            for (int n = 0; n < 8; ++n) fa[n] += acc[n][i];
        }
    }
    if (cege >= 0) {
#pragma unroll
        for (int n = 0; n < 8; ++n)
            atomicAdd(&egoF[(size_t)cege * 512 + it * HH + n * 16 + c16], fa[n]);
    }
}

// ---------------------------------------------------------------------------
// K6: filter-graph features (largest component + soft-WL on 8-node graphs).
// ---------------------------------------------------------------------------
__global__ __launch_bounds__(256) void k_filt(const float* __restrict__ P,
                                              const int* __restrict__ buckF,
                                              const float* __restrict__ Rg,
                                              float* __restrict__ filtF,
                                              float* __restrict__ fnorm) {
    __shared__ float As[MM][MM];
    __shared__ float Am[MM][MM];
    __shared__ float msk[MM];
    __shared__ float cbuf[2][MM][HH];
    __shared__ float ubuf[MM][HH];
    __shared__ float feats[4 * HH];
    __shared__ float red4[4];
    int f = blockIdx.x, tid = threadIdx.x, wave = tid >> 6, lane = tid & 63;
    if (tid < 64) As[tid >> 3][tid & 7] = P[f * 64 + tid];
    for (int idx = tid; idx < 4 * HH; idx += 256) feats[idx] = 0.f;
    __syncthreads();
    if (tid == 0) {
        float comp[MM];
        for (int m = 0; m < MM; ++m) comp[m] = (float)m;
        for (int it = 0; it < MM; ++it) {
            float nm[MM];
            for (int j = 0; j < MM; ++j) {
                float mn = 1e9f;
                for (int k = 0; k < MM; ++k)
                    if (As[j][k] > 0.f) mn = fminf(mn, comp[k]);
                nm[j] = mn;
            }
            for (int j = 0; j < MM; ++j) comp[j] = fminf(comp[j], nm[j]);
        }
        int cnt[MM], ci[MM];
        for (int m = 0; m < MM; ++m) cnt[m] = 0;
        for (int m = 0; m < MM; ++m) { ci[m] = (int)comp[m]; cnt[ci[m]]++; }
        int best = 0;
        for (int m = 1; m < MM; ++m) if (cnt[m] > cnt[best]) best = m;   // first max
        for (int m = 0; m < MM; ++m) msk[m] = (ci[m] == best) ? 1.0f : 0.0f;
    }
    __syncthreads();
    if (tid < 64) Am[tid >> 3][tid & 7] = As[tid >> 3][tid & 7] * msk[tid >> 3] * msk[tid & 7];
    for (int idx = tid; idx < MM * HH; idx += 256) {
        int m = idx >> 7, h = idx & 127;
        cbuf[0][m][h] = (msk[m] > 0.f && h == buckF[f * MM + m]) ? 1.0f : 0.0f;
    }
    __syncthreads();
    if (tid < HH) {
        float s = 0.f;
        for (int m = 0; m < MM; ++m) s += cbuf[0][m][tid];
        feats[tid] = s;
    }
    __syncthreads();
    int cur = 0;
    int h2 = 2 * lane;
    for (int it = 1; it <= 3; ++it) {
#pragma unroll
        for (int jj = 0; jj < 2; ++jj) {
            int d = wave * 2 + jj;
            float u0 = 0.f, u1 = 0.f;
            for (int s = 0; s < MM; ++s) {
                float w = Am[d][s];
                u0 += w * cbuf[cur][s][h2];
                u1 += w * cbuf[cur][s][h2 + 1];
            }
            ubuf[d][h2] = u0;
            ubuf[d][h2 + 1] = u1;
        }
        float a0[2] = {0.f, 0.f}, a1[2] = {0.f, 0.f};
        for (int k = 0; k < HH; ++k) {
            float2 rt = *(const float2*)&Rg[(size_t)k * HH + h2];
            float2 rb = *(const float2*)&Rg[(size_t)(HH + k) * HH + h2];
#pragma unroll
            for (int jj = 0; jj < 2; ++jj) {
                int d = wave * 2 + jj;
                float cd = cbuf[cur][d][k];
                float ud = ubuf[d][k];
                a0[jj] += cd * rt.x + ud * rb.x;
                a1[jj] += cd * rt.y + ud * rb.y;
            }
        }
#pragma unroll
        for (int jj = 0; jj < 2; ++jj) {
            int d = wave * 2 + jj;
            float z0 = a0[jj], z1 = a1[jj];
            float m = fmaxf(z0, z1);
            for (int off = 32; off > 0; off >>= 1) m = fmaxf(m, __shfl_xor(m, off));
            float e0 = exp2f((z0 - m) * TAU_SCALE);
            float e1 = exp2f((z1 - m) * TAU_SCALE);
            float s = e0 + e1;
            for (int off = 32; off > 0; off >>= 1) s += __shfl_xor(s, off);
            float inv = msk[d] / s;
            float c0 = e0 * inv, c1 = e1 * inv;
            cbuf[1 - cur][d][h2] = c0;
            cbuf[1 - cur][d][h2 + 1] = c1;
            atomicAdd(&feats[it * HH + h2], c0);
            atomicAdd(&feats[it * HH + h2 + 1], c1);
        }
        __syncthreads();
        cur = 1 - cur;
    }
    float np = 0.f;
    for (int idx = tid; idx < 4 * HH; idx += 256) {
        float v = feats[idx];
        filtF[(size_t)f * 512 + idx] = v;
        np += v * v;
    }
    for (int off = 32; off > 0; off >>= 1) np += __shfl_xor(np, off);
    if (lane == 0) red4[wave] = np;
    __syncthreads();
    if (tid == 0) fnorm[f] = sqrtf(red4[0] + red4[1] + red4[2] + red4[3]);
}

// ---------------------------------------------------------------------------
// K7: normalized similarity out[i][f].
// ---------------------------------------------------------------------------
__global__ __launch_bounds__(64) void k_sim(const float* __restrict__ egoF,
                                            const float* __restrict__ filtF,
                                            const float* __restrict__ fnorm,
                                            float* __restrict__ out) {
    int i = blockIdx.x, lane = threadIdx.x;
    float e[8];
    float ss = 0.f;
#pragma unroll
    for (int r = 0; r < 8; ++r) {
        e[r] = egoF[(size_t)i * 512 + r * 64 + lane];
        ss += e[r] * e[r];
    }
    for (int off = 32; off > 0; off >>= 1) ss += __shfl_xor(ss, off);
    float ng = sqrtf(ss);
    for (int f = 0; f < FF; ++f) {
        float d = 0.f;
#pragma unroll
        for (int r = 0; r < 8; ++r) d += e[r] * filtF[(size_t)f * 512 + r * 64 + lane];
        for (int off = 32; off > 0; off >>= 1) d += __shfl_xor(d, off);
        if (lane == 0) out[i * FF + f] = d / (fnorm[f] * ng + 1e-12f);
    }
}

extern "C" void kernel_launch(void* const* d_in, const int* in_sizes, int n_in,
                              void* d_out, int out_size, void* d_ws, size_t ws_size,
                              hipStream_t stream) {
    (void)in_sizes; (void)n_in; (void)out_size; (void)ws_size;
    const float* x  = (const float*)d_in[0];
    const int*   ei = (const int*)d_in[1];
    const float* P  = (const float*)d_in[2];
    const float* X  = (const float*)d_in[3];
    const float* E0 = (const float*)d_in[4];
    const float* Rg = (const float*)d_in[5];
    float* out = (float*)d_out;
    char* ws = (char*)d_ws;

    unsigned long long* adj   = (unsigned long long*)(ws + OFF_ADJ);
    int* degN   = (int*)(ws + OFF_DEG);
    int* count  = (int*)(ws + OFF_CNT);
    int* rowOff = (int*)(ws + OFF_ROFF);
    int* buckN  = (int*)(ws + OFF_BUCKN);
    int* buckF  = (int*)(ws + OFF_BUCKF);
    unsigned short* nbrLstN = (unsigned short*)(ws + OFF_NLST);
    unsigned short* cego    = (unsigned short*)(ws + OFF_CEGO);
    unsigned short* nbrCnt  = (unsigned short*)(ws + OFF_NCNT);
    unsigned short* rowBuck = (unsigned short*)(ws + OFF_RBK);
    unsigned short* nbrRow  = (unsigned short*)(ws + OFF_NBR);
    unsigned short* nbrBuck = (unsigned short*)(ws + OFF_NBK);
    float* egoF  = (float*)(ws + OFF_EGOF);
    float* filtF = (float*)(ws + OFF_FILTF);
    float* fnorm = (float*)(ws + OFF_FNORM);
    float* cA    = (float*)(ws + OFF_CA);
    float* cB    = (float*)(ws + OFF_CB);
    // bitsR scratch lives in the (not-yet-used) cA buffer
    unsigned long long* bitsR = (unsigned long long*)(ws + OFF_CA);
    short* RtH = (short*)(ws + OFF_RT);
    short* RtL = RtH + (size_t)HH * 256;

    hipMemsetAsync(ws, 0, OFF_CNT, stream);   // zero adj + degN
    k_build<<<(EE + NN + FF * MM + 4096 + 255) / 256, 256, 0, stream>>>(
        ei, x, X, E0, Rg, degN, nbrLstN, adj, buckN, buckF, RtH, RtL);
    // filter features are independent of the ego pipeline — overlap them here
    k_filt<<<FF, 256, 0, stream>>>(P, buckF, Rg, filtF, fnorm);
    k_reach<<<NN, 256, 0, stream>>>(adj, bitsR, count);
    k_pack<<<NN, 64, 0, stream>>>(bitsR, count, rowOff, degN, nbrLstN, buckN,
                                  nbrRow, nbrBuck, nbrCnt, rowBuck, cego, egoF);
    // iteration 1 (sparse, Rbot in LDS)
    k_iter1<<<NN, 256, 0, stream>>>(count, rowOff, rowBuck, nbrBuck, nbrCnt, Rg, cB, egoF);
    // iterations 2,3: MFMA hi/lo-split GEMM, 4 independent 16-row tiles/block
    k_iter<<<CAP_ROWS / 64, 256, 0, stream>>>(cB, cA, RtH, RtL, rowOff, nbrRow, nbrCnt, cego, egoF, 2);
    k_iter<<<CAP_ROWS / 64, 256, 0, stream>>>(cA, cB, RtH, RtL, rowOff, nbrRow, nbrCnt, cego, egoF, 3);
    k_sim<<<NN, 64, 0, stream>>>(egoF, filtF, fnorm, out);
}

// Round 11
// 301.804 us; speedup vs baseline: 1.0520x; 1.0520x over previous
//
#include <hip/hip_runtime.h>
#include <hip/hip_bf16.h>

// Problem constants (fixed by reference)
#define NN 512
#define EE 2048
#define LL 16
#define FF 16
#define MM 8
#define HH 128
#define CAP_ROWS 40960             // packed rows across all egos (~34k expected, u16 ids)
#define MAXD 32                    // per-node / per-row neighbor capacity (avg deg ~8)
#define TAU_SCALE 14.426950408889634f   // log2(e)/TAU, TAU=0.1

typedef __attribute__((ext_vector_type(8))) short bf16x8;   // 8 bf16 = 4 VGPR
typedef __attribute__((ext_vector_type(8))) unsigned short u16x8;
typedef __attribute__((ext_vector_type(4))) float f32x4;

// ---- workspace layout (bytes) ----
constexpr size_t OFF_ADJ   = 0;                              // u64[512*8] adjacency bitsets (memset)
constexpr size_t SZ_ADJ    = (size_t)NN * 8 * 8;
constexpr size_t OFF_DEG   = OFF_ADJ + SZ_ADJ;               // int[512] node degree (memset)
constexpr size_t SZ_DEG    = (size_t)NN * 4;
constexpr size_t OFF_CNT   = OFF_DEG + SZ_DEG;               // int[512] ego node counts
constexpr size_t SZ_CNT    = (size_t)NN * 4;
constexpr size_t OFF_ROFF  = OFF_CNT + SZ_CNT;               // int[513] packed row offsets
constexpr size_t SZ_ROFF   = (size_t)(NN + 1) * 4 + 12;
constexpr size_t OFF_BUCKN = OFF_ROFF + SZ_ROFF;             // int[512] node -> WL bucket
constexpr size_t SZ_BUCKN  = (size_t)NN * 4;
constexpr size_t OFF_BUCKF = OFF_BUCKN + SZ_BUCKN;           // int[128]
constexpr size_t SZ_BUCKF  = (size_t)FF * MM * 4;
constexpr size_t OFF_NLST  = ((OFF_BUCKF + SZ_BUCKF + 63) / 64) * 64;  // u16[512*32] node nbr lists
constexpr size_t SZ_NLST   = (size_t)NN * MAXD * 2;
constexpr size_t OFF_CEGO  = OFF_NLST + SZ_NLST;             // u16[CAP] row -> ego
constexpr size_t SZ_CEGO   = (size_t)CAP_ROWS * 2;
constexpr size_t OFF_NCNT  = OFF_CEGO + SZ_CEGO;             // u16[CAP] row nbr count
constexpr size_t SZ_NCNT   = (size_t)CAP_ROWS * 2;
constexpr size_t OFF_RBK   = OFF_NCNT + SZ_NCNT;             // u16[CAP] row -> own bucket
constexpr size_t SZ_RBK    = (size_t)CAP_ROWS * 2;
constexpr size_t OFF_NBR   = OFF_RBK + SZ_RBK;               // u16[CAP*32] row nbr -> packed row id
constexpr size_t SZ_NBR    = (size_t)CAP_ROWS * MAXD * 2;
constexpr size_t OFF_NBK   = OFF_NBR + SZ_NBR;               // u16[CAP*32] row nbr -> bucket
constexpr size_t SZ_NBK    = (size_t)CAP_ROWS * MAXD * 2;
constexpr size_t OFF_EGOF  = ((OFF_NBK + SZ_NBK + 63) / 64) * 64;      // f32[512*512] ego feats
constexpr size_t SZ_EGOF   = (size_t)NN * 512 * 4;
constexpr size_t OFF_FILTF = OFF_EGOF + SZ_EGOF;             // f32[16*512]
constexpr size_t SZ_FILTF  = (size_t)FF * 512 * 4;
constexpr size_t OFF_FNORM = OFF_FILTF + SZ_FILTF;           // f32[16]
constexpr size_t SZ_FNORM  = 64;
constexpr size_t OFF_CA    = ((OFF_FNORM + SZ_FNORM + 255) / 256) * 256; // c buf A [CAP*128] f32
constexpr size_t SZ_CBUF   = (size_t)CAP_ROWS * HH * 4;      // 20 MB
constexpr size_t OFF_CB    = OFF_CA + SZ_CBUF;               // c buf B
constexpr size_t OFF_RT    = OFF_CB + SZ_CBUF;               // bf16 RtH (64K) + RtL (64K)
// total ~ 49.5 MB

// ---- bf16 split helpers (RNE) ----
__device__ __forceinline__ unsigned f2bfbits(float x) {
    unsigned u = __float_as_uint(x);
    return (u + 0x7fffu + ((u >> 16) & 1u)) >> 16;
}
__device__ __forceinline__ float bf2f(unsigned hb) { return __uint_as_float(hb << 16); }

// XCD-aware bijective block swizzle (requires nwg % 8 == 0): XCD k gets a
// CONTIGUOUS chunk of the grid -> intra-ego gathers stay in k's private L2.
__device__ __forceinline__ int xcd_swz(int bid, int nwg) {
    int cpx = nwg >> 3;
    return (bid & 7) * cpx + (bid >> 3);
}

// ---------------------------------------------------------------------------
// K1: node degree + nbr lists + adjacency bitsets + bucket lookups
//     + (merged) R -> transposed bf16 hi/lo Rt[col][k].
// ---------------------------------------------------------------------------
__global__ __launch_bounds__(256) void k_build(const int* __restrict__ ei,
                                               const float* __restrict__ x,
                                               const float* __restrict__ X,
                                               const float* __restrict__ E0,
                                               const float* __restrict__ Rg,
                                               int* __restrict__ degN,
                                               unsigned short* __restrict__ nbrLstN,
                                               unsigned long long* __restrict__ adj,
                                               int* __restrict__ buckN,
                                               int* __restrict__ buckF,
                                               short* __restrict__ RtH,
                                               short* __restrict__ RtL) {
    int idx = blockIdx.x * blockDim.x + threadIdx.x;
    if (idx < EE) {
        int a = ei[idx], b = ei[EE + idx];
        int p = atomicAdd(&degN[a], 1);
        if (p < MAXD) nbrLstN[(size_t)a * MAXD + p] = (unsigned short)b;
        int q = atomicAdd(&degN[b], 1);
        if (q < MAXD) nbrLstN[(size_t)b * MAXD + q] = (unsigned short)a;
        atomicOr(&adj[(size_t)a * 8 + (b >> 6)], 1ull << (b & 63));
        atomicOr(&adj[(size_t)b * 8 + (a >> 6)], 1ull << (a & 63));
    } else if (idx < EE + NN) {
        int i = idx - EE;
        int lab = 0;
        for (int l = 0; l < LL; ++l) if (x[i * LL + l] > 0.5f) lab = l;
        int b = 0;
        for (int h = 0; h < HH; ++h) if (E0[lab * HH + h] > 0.5f) b = h;
        buckN[i] = b;
    } else if (idx < EE + NN + FF * MM) {
        int fm = idx - EE - NN;
        int lab = 0;
        for (int l = 0; l < LL; ++l) if (X[fm * LL + l] > 0.5f) lab = l;
        int b = 0;
        for (int h = 0; h < HH; ++h) if (E0[lab * HH + h] > 0.5f) b = h;
        buckF[fm] = b;
    } else if (idx < EE + NN + FF * MM + 4096) {
        int pidx = idx - (EE + NN + FF * MM);
        int col = pidx >> 5;
        int kc = (pidx & 31) * 8;
        bf16x8 hv, lv;
#pragma unroll
        for (int j = 0; j < 8; ++j) {
            float xv = Rg[(size_t)(kc + j) * HH + col];
            unsigned hb = f2bfbits(xv);
            hv[j] = (short)hb;
            lv[j] = (short)f2bfbits(xv - bf2f(hb));
        }
        *(bf16x8*)&RtH[(size_t)col * 256 + kc] = hv;
        *(bf16x8*)&RtL[(size_t)col * 256 + kc] = lv;
    }
}

// ---------------------------------------------------------------------------
// K2: 2-hop reach bitsets + counts (256 threads, 4 waves x 2 bit-words).
// ---------------------------------------------------------------------------
__global__ __launch_bounds__(256, 2) void k_reach(const unsigned long long* __restrict__ adj,
                                                  unsigned long long* __restrict__ bitsR,
                                                  int* __restrict__ count) {
    __shared__ unsigned long long r1[8];
    __shared__ unsigned long long r2[8];
    int i = blockIdx.x, tid = threadIdx.x;
    int t = tid & 63, w = tid >> 6;
    if (tid < 8) {
        unsigned long long v = adj[(size_t)i * 8 + tid];
        if (tid == (i >> 6)) v |= 1ull << (i & 63);
        r1[tid] = v;
        r2[tid] = v;
    }
    __syncthreads();
    unsigned long long p[8] = {0, 0, 0, 0, 0, 0, 0, 0};
#pragma unroll
    for (int rr = 0; rr < 2; ++rr) {
        int rep = 2 * w + rr;
        if ((r1[rep] >> t) & 1ull) {
            int j = t + rep * 64;
#pragma unroll
            for (int w2 = 0; w2 < 8; ++w2) p[w2] |= adj[(size_t)j * 8 + w2];
        }
    }
#pragma unroll
    for (int w2 = 0; w2 < 8; ++w2)
        if (p[w2]) atomicOr(&r2[w2], p[w2]);
    __syncthreads();
    if (tid < 8) bitsR[(size_t)i * 8 + tid] = r2[tid];
    if (tid == 0) {
        int acc = 0;
        for (int w2 = 0; w2 < 8; ++w2) acc += __popcll(r2[w2]);
        count[i] = acc;
    }
}

// ---------------------------------------------------------------------------
// K3: pack egos into flat row space (inline prefix scan, writes rowOff).
// ---------------------------------------------------------------------------
__global__ __launch_bounds__(64) void k_pack(const unsigned long long* __restrict__ bitsR,
                                             const int* __restrict__ count,
                                             int* __restrict__ rowOff,
                                             const int* __restrict__ degN,
                                             const unsigned short* __restrict__ nbrLstN,
                                             const int* __restrict__ buckN,
                                             unsigned short* __restrict__ nbrRow,
                                             unsigned short* __restrict__ nbrBuck,
                                             unsigned short* __restrict__ nbrCnt,
                                             unsigned short* __restrict__ rowBuck,
                                             unsigned short* __restrict__ cegoG,
                                             float* __restrict__ egoF) {
    __shared__ unsigned long long bits[8];
    __shared__ int wpre[8];
    __shared__ unsigned short cmap_s[NN];
    __shared__ unsigned short nodes_s[NN];
    __shared__ int buckS[NN];
    __shared__ float f0[HH];
    int i = blockIdx.x, t = threadIdx.x;
    // ---- inline exclusive prefix: base = sum(count[0..i-1]) ----
    int pre = 0;
#pragma unroll
    for (int j = 0; j < 8; ++j) {
        int idx = t * 8 + j;
        int cj = count[idx];
        if (idx < i) pre += cj;
    }
    for (int off = 32; off > 0; off >>= 1) pre += __shfl_xor(pre, off);
    int base = pre;
    if (t == 0) {
        rowOff[i] = base;
        if (i == NN - 1) rowOff[NN] = base + count[i];
    }
    if (t < 8) bits[t] = bitsR[(size_t)i * 8 + t];
    { f0[t] = 0.0f; f0[t + 64] = 0.0f; }
    for (int j = t; j < NN; j += 64) buckS[j] = buckN[j];
    __syncthreads();
    if (t == 0) {
        int acc = 0;
        for (int w = 0; w < 8; ++w) { wpre[w] = acc; acc += __popcll(bits[w]); }
    }
    __syncthreads();
    int n = count[i];
    if (base >= CAP_ROWS) n = 0;
    else if (base + n > CAP_ROWS) n = CAP_ROWS - base;
    for (int rep = 0; rep < 8; ++rep) {
        int j = t + rep * 64;
        unsigned long long word = bits[rep];
        unsigned short v = 0xFFFFu;
        if ((word >> t) & 1ull) {
            int idx = wpre[rep] + __popcll(word & ((1ull << t) - 1ull));
            if (idx < n) { v = (unsigned short)idx; nodes_s[idx] = (unsigned short)j; }
        }
        cmap_s[j] = v;
    }
    // zero iter 2..3 feats region (iter 0,1 fully overwritten)
    for (int q = 256 + t; q < 512; q += 64) egoF[(size_t)i * 512 + q] = 0.0f;
    __syncthreads();
    for (int m = t; m < n; m += 64) {
        int j = nodes_s[m];
        int b = buckS[j];
        atomicAdd(&f0[b], 1.0f);
        size_t row = (size_t)(base + m);
        rowBuck[row] = (unsigned short)b;
        int dn = degN[j]; if (dn > MAXD) dn = MAXD;
        int cnt = 0;
        for (int eb = 0; eb < dn; eb += 8) {
            u16x8 nv = *(const u16x8*)&nbrLstN[(size_t)j * MAXD + eb];
#pragma unroll
            for (int j8 = 0; j8 < 8; ++j8) {
                if (eb + j8 < dn) {
                    unsigned short nbNode = nv[j8];
                    unsigned short nr = cmap_s[nbNode];
                    if (nr != 0xFFFFu && cnt < MAXD) {
                        nbrRow[row * MAXD + cnt] = (unsigned short)(base + nr);
                        nbrBuck[row * MAXD + cnt] = (unsigned short)buckS[nbNode];
                        cnt++;
                    }
                }
            }
        }
        nbrCnt[row] = (unsigned short)cnt;
        cegoG[row] = (unsigned short)i;
    }
    __syncthreads();
    if (t < 64) {
        egoF[(size_t)i * 512 + t] = f0[t];
        egoF[(size_t)i * 512 + t + 64] = f0[t + 64];
    }
}

// ---------------------------------------------------------------------------
// K4: iteration 1, sparse form (Rbot staged in LDS — r9, neutral-or-better).
// ---------------------------------------------------------------------------
__global__ __launch_bounds__(256, 2) void k_iter1(const int* __restrict__ count,
                                                  const int* __restrict__ rowOff,
                                                  const unsigned short* __restrict__ rowBuck,
                                                  const unsigned short* __restrict__ nbrBuck,
                                                  const unsigned short* __restrict__ nbrCnt,
                                                  const float* __restrict__ Rg,
                                                  float* __restrict__ cOut,
                                                  float* __restrict__ egoF) {
    __shared__ float RbS[HH * HH];      // 64 KB: Rbot rows, linear
    __shared__ float fs[HH];
    int i = xcd_swz(blockIdx.x, NN);
    int tid = threadIdx.x;
    int base = rowOff[i];
    int n = count[i];
    if (base >= CAP_ROWS) n = 0;
    else if (base + n > CAP_ROWS) n = CAP_ROWS - base;
    if (tid < HH) fs[tid] = 0.0f;
    // ---- stage Rbot -> LDS (coalesced float4 stream) ----
    {
        const float4* src = (const float4*)(Rg + (size_t)HH * HH);
        float4* dst = (float4*)RbS;
        for (int idx = tid; idx < (HH * HH) / 4; idx += 256) dst[idx] = src[idx];
    }
    __syncthreads();
    int col = (tid & 7) * 16;
    float facc[16];
#pragma unroll
    for (int q = 0; q < 16; ++q) facc[q] = 0.0f;
    for (int m = tid >> 3; m < n; m += 32) {
        int gr = base + m;
        float z[16];
        const float* rt = Rg + (size_t)rowBuck[gr] * HH + col;
#pragma unroll
        for (int q = 0; q < 4; ++q) *(float4*)&z[q * 4] = *(const float4*)&rt[q * 4];
        int cnt = nbrCnt[gr];
        const unsigned short* nk = &nbrBuck[(size_t)gr * MAXD];
        for (int eb = 0; eb < cnt; eb += 8) {
            u16x8 nv = *(const u16x8*)&nk[eb];
#pragma unroll
            for (int j = 0; j < 8; ++j) {
                if (eb + j < cnt) {
                    const float* rb = RbS + (size_t)nv[j] * HH + col;
#pragma unroll
                    for (int q = 0; q < 4; ++q) {
                        float4 rv = *(const float4*)&rb[q * 4];
                        z[q * 4 + 0] += rv.x; z[q * 4 + 1] += rv.y;
                        z[q * 4 + 2] += rv.z; z[q * 4 + 3] += rv.w;
                    }
                }
            }
        }
        float mx = z[0];
#pragma unroll
        for (int q = 1; q < 16; ++q) mx = fmaxf(mx, z[q]);
        for (int off = 4; off > 0; off >>= 1) mx = fmaxf(mx, __shfl_xor(mx, off));
        float s = 0.0f;
#pragma unroll
        for (int q = 0; q < 16; ++q) { z[q] = exp2f((z[q] - mx) * TAU_SCALE); s += z[q]; }
        for (int off = 4; off > 0; off >>= 1) s += __shfl_xor(s, off);
        float inv = 1.0f / s;
        float* crow = cOut + (size_t)gr * HH + col;
#pragma unroll
        for (int q = 0; q < 16; ++q) { z[q] *= inv; facc[q] += z[q]; }
#pragma unroll
        for (int q = 0; q < 4; ++q) *(float4*)&crow[q * 4] = *(const float4*)&z[q * 4];
    }
#pragma unroll
    for (int q = 0; q < 16; ++q) atomicAdd(&fs[col + q], facc[q]);
    __syncthreads();
    if (tid < HH) egoF[(size_t)i * 512 + HH + tid] = fs[tid];
}

// ---------------------------------------------------------------------------
// K5: fused soft-WL iteration (it=2,3) — r7 structure (best measured),
// with the neighbor-index loads issued BEFORE the own-c loads so the index
// s_waitcnt overlaps the own-c flight.  Arithmetic bit-identical to r7.
// ---------------------------------------------------------------------------
__global__ __launch_bounds__(64, 1) void k_iter(const float* __restrict__ cur,
                                                float* __restrict__ nxt,
                                                const short* __restrict__ RtH,
                                                const short* __restrict__ RtL,
                                                const int* __restrict__ rowOff,
                                                const unsigned short* __restrict__ nbrRow,
                                                const unsigned short* __restrict__ nbrCnt,
                                                const unsigned short* __restrict__ cegoG,
                                                float* __restrict__ egoF,
                                                int it) {
    int Rtot = rowOff[NN];
    if (Rtot > CAP_ROWS) Rtot = CAP_ROWS;
    int r0 = xcd_swz(blockIdx.x, gridDim.x) * 16;
    if (r0 >= Rtot) return;
    int tid = threadIdx.x;
    int c16 = tid & 15, g = tid >> 4;
    int kb = g * 8;                       // this lane's 8-k slice within each 32-k tile
    int grA = r0 + c16;                   // A-row this lane feeds (clamped for loads)
    if (grA >= Rtot) grA = Rtot - 1;

    // ---- neighbor count + index chunks first (resolve while own-c flies) ----
    int cnt = nbrCnt[grA];
    const unsigned short* nb = &nbrRow[(size_t)grA * MAXD];
    u16x8 nv0 = *(const u16x8*)&nb[0];
    u16x8 nv1 = *(const u16x8*)&nb[8];
    u16x8 nv2 = *(const u16x8*)&nb[16];
    u16x8 nv3 = *(const u16x8*)&nb[24];

    // ---- own-c fragment loads (independent, in flight early) ----
    const float* crOwn = &cur[(size_t)grA * HH + kb];
    float4 oc[8];
#pragma unroll
    for (int t = 0; t < 4; ++t) {
        oc[2 * t]     = *(const float4*)&crOwn[t * 32];
        oc[2 * t + 1] = *(const float4*)&crOwn[t * 32 + 4];
    }

    // ---- gather u slices: chunked indices, add order == r1 ----
    float ua[4][8];
#pragma unroll
    for (int s = 0; s < 4; ++s)
#pragma unroll
        for (int j = 0; j < 8; ++j) ua[s][j] = 0.0f;
#pragma unroll
    for (int cb = 0; cb < 4; ++cb) {
        u16x8 nv = (cb == 0) ? nv0 : (cb == 1) ? nv1 : (cb == 2) ? nv2 : nv3;
        int eb = cb * 8;
        if (eb < cnt) {
#pragma unroll
            for (int j = 0; j < 8; ++j) {
                if (eb + j < cnt) {
                    const float* cr = &cur[(size_t)nv[j] * HH + kb];
#pragma unroll
                    for (int s = 0; s < 4; ++s) {
                        float4 v0 = *(const float4*)&cr[s * 32];
                        float4 v1 = *(const float4*)&cr[s * 32 + 4];
                        ua[s][0] += v0.x; ua[s][1] += v0.y; ua[s][2] += v0.z; ua[s][3] += v0.w;
                        ua[s][4] += v1.x; ua[s][5] += v1.y; ua[s][6] += v1.z; ua[s][7] += v1.w;
                    }
                }
            }
        }
    }

    f32x4 acc[8];
#pragma unroll
    for (int n = 0; n < 8; ++n) acc[n] = (f32x4)(0.0f);
    const short* bbH = RtH + (size_t)c16 * 256 + kb;
    const short* bbL = RtL + (size_t)c16 * 256 + kb;

    // ---- u ktiles (t = s+4), converting+releasing one 8-reg slice at a time ----
#pragma unroll
    for (int s = 0; s < 4; ++s) {
        bf16x8 ahi, alo;
#pragma unroll
        for (int j = 0; j < 8; ++j) {
            float xv = ua[s][j];
            unsigned hb = f2bfbits(xv);
            ahi[j] = (short)hb;
            alo[j] = (short)f2bfbits(xv - bf2f(hb));
        }
        const int t = s + 4;
#pragma unroll
        for (int n = 0; n < 8; ++n) {
            bf16x8 bh = *(const bf16x8*)&bbH[n * 4096 + t * 32];
            bf16x8 bl = *(const bf16x8*)&bbL[n * 4096 + t * 32];
            acc[n] = __builtin_amdgcn_mfma_f32_16x16x32_bf16(ahi, bh, acc[n], 0, 0, 0);
            acc[n] = __builtin_amdgcn_mfma_f32_16x16x32_bf16(ahi, bl, acc[n], 0, 0, 0);
            acc[n] = __builtin_amdgcn_mfma_f32_16x16x32_bf16(alo, bh, acc[n], 0, 0, 0);
        }
    }
    // ---- c ktiles (t = 0..3), from the hoisted oc regs ----
    {
#pragma unroll
        for (int t = 0; t < 4; ++t) {
            float4 v0 = oc[2 * t];
            float4 v1 = oc[2 * t + 1];
            float cv[8] = {v0.x, v0.y, v0.z, v0.w, v1.x, v1.y, v1.z, v1.w};
            bf16x8 ahi, alo;
#pragma unroll
            for (int j = 0; j < 8; ++j) {
                unsigned hb = f2bfbits(cv[j]);
                ahi[j] = (short)hb;
                alo[j] = (short)f2bfbits(cv[j] - bf2f(hb));
            }
#pragma unroll
            for (int n = 0; n < 8; ++n) {
                bf16x8 bh = *(const bf16x8*)&bbH[n * 4096 + t * 32];
                bf16x8 bl = *(const bf16x8*)&bbL[n * 4096 + t * 32];
                acc[n] = __builtin_amdgcn_mfma_f32_16x16x32_bf16(ahi, bh, acc[n], 0, 0, 0);
                acc[n] = __builtin_amdgcn_mfma_f32_16x16x32_bf16(ahi, bl, acc[n], 0, 0, 0);
                acc[n] = __builtin_amdgcn_mfma_f32_16x16x32_bf16(alo, bh, acc[n], 0, 0, 0);
            }
        }
    }

    // ---- softmax per output row (row = 4g+i lives in 16 lanes x 8 regs) ----
    float inv[4];
#pragma unroll
    for (int i = 0; i < 4; ++i) {
        float m = acc[0][i];
#pragma unroll
        for (int n = 1; n < 8; ++n) m = fmaxf(m, acc[n][i]);
        for (int off = 8; off > 0; off >>= 1) m = fmaxf(m, __shfl_xor(m, off));
        float s = 0.0f;
#pragma unroll
        for (int n = 0; n < 8; ++n) {
            float e = exp2f((acc[n][i] - m) * TAU_SCALE);
            acc[n][i] = e; s += e;
        }
        for (int off = 8; off > 0; off >>= 1) s += __shfl_xor(s, off);
        inv[i] = 1.0f / s;
    }

    // ---- store c_next + per-ego feature accumulation ----
    float fa[8];
#pragma unroll
    for (int n = 0; n < 8; ++n) fa[n] = 0.0f;
    int cege = -1;
#pragma unroll
    for (int i = 0; i < 4; ++i) {
        int gr = r0 + g * 4 + i;
        if (gr < Rtot) {
#pragma unroll
            for (int n = 0; n < 8; ++n) {
                float c = acc[n][i] * inv[i];
                nxt[(size_t)gr * HH + n * 16 + c16] = c;
                acc[n][i] = c;
            }
            int ego = cegoG[gr];
            if (ego != cege) {
                if (cege >= 0) {
#pragma unroll
                    for (int n = 0; n < 8; ++n) {
                        atomicAdd(&egoF[(size_t)cege * 512 + it * HH + n * 16 + c16], fa[n]);
                        fa[n] = 0.0f;
                    }
                }
                cege = ego;
            }
#pragma unroll
            for (int n = 0; n < 8; ++n) fa[n] += acc[n][i];
        }
    }
    if (cege >= 0) {
#pragma unroll
        for (int n = 0; n < 8; ++n)
            atomicAdd(&egoF[(size_t)cege * 512 + it * HH + n * 16 + c16], fa[n]);
    }
}

// ---------------------------------------------------------------------------
// K6: filter-graph features (largest component + soft-WL on 8-node graphs).
// ---------------------------------------------------------------------------
__global__ __launch_bounds__(256) void k_filt(const float* __restrict__ P,
                                              const int* __restrict__ buckF,
                                              const float* __restrict__ Rg,
                                              float* __restrict__ filtF,
                                              float* __restrict__ fnorm) {
    __shared__ float As[MM][MM];
    __shared__ float Am[MM][MM];
    __shared__ float msk[MM];
    __shared__ float cbuf[2][MM][HH];
    __shared__ float ubuf[MM][HH];
    __shared__ float feats[4 * HH];
    __shared__ float red4[4];
    int f = blockIdx.x, tid = threadIdx.x, wave = tid >> 6, lane = tid & 63;
    if (tid < 64) As[tid >> 3][tid & 7] = P[f * 64 + tid];
    for (int idx = tid; idx < 4 * HH; idx += 256) feats[idx] = 0.f;
    __syncthreads();
    if (tid == 0) {
        float comp[MM];
        for (int m = 0; m < MM; ++m) comp[m] = (float)m;
        for (int it = 0; it < MM; ++it) {
            float nm[MM];
            for (int j = 0; j < MM; ++j) {
                float mn = 1e9f;
                for (int k = 0; k < MM; ++k)
                    if (As[j][k] > 0.f) mn = fminf(mn, comp[k]);
                nm[j] = mn;
            }
            for (int j = 0; j < MM; ++j) comp[j] = fminf(comp[j], nm[j]);
        }
        int cnt[MM], ci[MM];
        for (int m = 0; m < MM; ++m) cnt[m] = 0;
        for (int m = 0; m < MM; ++m) { ci[m] = (int)comp[m]; cnt[ci[m]]++; }
        int best = 0;
        for (int m = 1; m < MM; ++m) if (cnt[m] > cnt[best]) best = m;   // first max
        for (int m = 0; m < MM; ++m) msk[m] = (ci[m] == best) ? 1.0f : 0.0f;
    }
    __syncthreads();
    if (tid < 64) Am[tid >> 3][tid & 7] = As[tid >> 3][tid & 7] * msk[tid >> 3] * msk[tid & 7];
    for (int idx = tid; idx < MM * HH; idx += 256) {
        int m = idx >> 7, h = idx & 127;
        cbuf[0][m][h] = (msk[m] > 0.f && h == buckF[f * MM + m]) ? 1.0f : 0.0f;
    }
    __syncthreads();
    if (tid < HH) {
        float s = 0.f;
        for (int m = 0; m < MM; ++m) s += cbuf[0][m][tid];
        feats[tid] = s;
    }
    __syncthreads();
    int cur = 0;
    int h2 = 2 * lane;
    for (int it = 1; it <= 3; ++it) {
#pragma unroll
        for (int jj = 0; jj < 2; ++jj) {
            int d = wave * 2 + jj;
            float u0 = 0.f, u1 = 0.f;
            for (int s = 0; s < MM; ++s) {
                float w = Am[d][s];
                u0 += w * cbuf[cur][s][h2];
                u1 += w * cbuf[cur][s][h2 + 1];
            }
            ubuf[d][h2] = u0;
            ubuf[d][h2 + 1] = u1;
        }
        float a0[2] = {0.f, 0.f}, a1[2] = {0.f, 0.f};
        for (int k = 0; k < HH; ++k) {
            float2 rt = *(const float2*)&Rg[(size_t)k * HH + h2];
            float2 rb = *(const float2*)&Rg[(size_t)(HH + k) * HH + h2];
#pragma unroll
            for (int jj = 0; jj < 2; ++jj) {
                int d = wave * 2 + jj;
                float cd = cbuf[cur][d][k];
                float ud = ubuf[d][k];
                a0[jj] += cd * rt.x + ud * rb.x;
                a1[jj] += cd * rt.y + ud * rb.y;
            }
        }
#pragma unroll
        for (int jj = 0; jj < 2; ++jj) {
            int d = wave * 2 + jj;
            float z0 = a0[jj], z1 = a1[jj];
            float m = fmaxf(z0, z1);
            for (int off = 32; off > 0; off >>= 1) m = fmaxf(m, __shfl_xor(m, off));
            float e0 = exp2f((z0 - m) * TAU_SCALE);
            float e1 = exp2f((z1 - m) * TAU_SCALE);
            float s = e0 + e1;
            for (int off = 32; off > 0; off >>= 1) s += __shfl_xor(s, off);
            float inv = msk[d] / s;
            float c0 = e0 * inv, c1 = e1 * inv;
            cbuf[1 - cur][d][h2] = c0;
            cbuf[1 - cur][d][h2 + 1] = c1;
            atomicAdd(&feats[it * HH + h2], c0);
            atomicAdd(&feats[it * HH + h2 + 1], c1);
        }
        __syncthreads();
        cur = 1 - cur;
    }
    float np = 0.f;
    for (int idx = tid; idx < 4 * HH; idx += 256) {
        float v = feats[idx];
        filtF[(size_t)f * 512 + idx] = v;
        np += v * v;
    }
    for (int off = 32; off > 0; off >>= 1) np += __shfl_xor(np, off);
    if (lane == 0) red4[wave] = np;
    __syncthreads();
    if (tid == 0) fnorm[f] = sqrtf(red4[0] + red4[1] + red4[2] + red4[3]);
}

// ---------------------------------------------------------------------------
// K7: normalized similarity out[i][f].
// ---------------------------------------------------------------------------
__global__ __launch_bounds__(64) void k_sim(const float* __restrict__ egoF,
                                            const float* __restrict__ filtF,
                                            const float* __restrict__ fnorm,
                                            float* __restrict__ out) {
    int i = blockIdx.x, lane = threadIdx.x;
    float e[8];
    float ss = 0.f;
#pragma unroll
    for (int r = 0; r < 8; ++r) {
        e[r] = egoF[(size_t)i * 512 + r * 64 + lane];
        ss += e[r] * e[r];
    }
    for (int off = 32; off > 0; off >>= 1) ss += __shfl_xor(ss, off);
    float ng = sqrtf(ss);
    for (int f = 0; f < FF; ++f) {
        float d = 0.f;
#pragma unroll
        for (int r = 0; r < 8; ++r) d += e[r] * filtF[(size_t)f * 512 + r * 64 + lane];
        for (int off = 32; off > 0; off >>= 1) d += __shfl_xor(d, off);
        if (lane == 0) out[i * FF + f] = d / (fnorm[f] * ng + 1e-12f);
    }
}

extern "C" void kernel_launch(void* const* d_in, const int* in_sizes, int n_in,
                              void* d_out, int out_size, void* d_ws, size_t ws_size,
                              hipStream_t stream) {
    (void)in_sizes; (void)n_in; (void)out_size; (void)ws_size;
    const float* x  = (const float*)d_in[0];
    const int*   ei = (const int*)d_in[1];
    const float* P  = (const float*)d_in[2];
    const float* X  = (const float*)d_in[3];
    const float* E0 = (const float*)d_in[4];
    const float* Rg = (const float*)d_in[5];
    float* out = (float*)d_out;
    char* ws = (char*)d_ws;

    unsigned long long* adj   = (unsigned long long*)(ws + OFF_ADJ);
    int* degN   = (int*)(ws + OFF_DEG);
    int* count  = (int*)(ws + OFF_CNT);
    int* rowOff = (int*)(ws + OFF_ROFF);
    int* buckN  = (int*)(ws + OFF_BUCKN);
    int* buckF  = (int*)(ws + OFF_BUCKF);
    unsigned short* nbrLstN = (unsigned short*)(ws + OFF_NLST);
    unsigned short* cego    = (unsigned short*)(ws + OFF_CEGO);
    unsigned short* nbrCnt  = (unsigned short*)(ws + OFF_NCNT);
    unsigned short* rowBuck = (unsigned short*)(ws + OFF_RBK);
    unsigned short* nbrRow  = (unsigned short*)(ws + OFF_NBR);
    unsigned short* nbrBuck = (unsigned short*)(ws + OFF_NBK);
    float* egoF  = (float*)(ws + OFF_EGOF);
    float* filtF = (float*)(ws + OFF_FILTF);
    float* fnorm = (float*)(ws + OFF_FNORM);
    float* cA    = (float*)(ws + OFF_CA);
    float* cB    = (float*)(ws + OFF_CB);
    // bitsR scratch lives in the (not-yet-used) cA buffer
    unsigned long long* bitsR = (unsigned long long*)(ws + OFF_CA);
    short* RtH = (short*)(ws + OFF_RT);
    short* RtL = RtH + (size_t)HH * 256;

    hipMemsetAsync(ws, 0, OFF_CNT, stream);   // zero adj + degN
    k_build<<<(EE + NN + FF * MM + 4096 + 255) / 256, 256, 0, stream>>>(
        ei, x, X, E0, Rg, degN, nbrLstN, adj, buckN, buckF, RtH, RtL);
    // filter features are independent of the ego pipeline — overlap them here
    k_filt<<<FF, 256, 0, stream>>>(P, buckF, Rg, filtF, fnorm);
    k_reach<<<NN, 256, 0, stream>>>(adj, bitsR, count);
    k_pack<<<NN, 64, 0, stream>>>(bitsR, count, rowOff, degN, nbrLstN, buckN,
                                  nbrRow, nbrBuck, nbrCnt, rowBuck, cego, egoF);
    // iteration 1 (sparse, Rbot in LDS)
    k_iter1<<<NN, 256, 0, stream>>>(count, rowOff, rowBuck, nbrBuck, nbrCnt, Rg, cB, egoF);
    // iterations 2,3: MFMA hi/lo-split GEMM, XCD-swizzled 16-row single-wave blocks
    k_iter<<<CAP_ROWS / 16, 64, 0, stream>>>(cB, cA, RtH, RtL, rowOff, nbrRow, nbrCnt, cego, egoF, 2);
    k_iter<<<CAP_ROWS / 16, 64, 0, stream>>>(cA, cB, RtH, RtL, rowOff, nbrRow, nbrCnt, cego, egoF, 3);
    k_sim<<<NN, 64, 0, stream>>>(egoF, filtF, fnorm, out);
}